// Round 4
// baseline (21450.409 us; speedup 1.0000x reference)
//
#include <hip/hip_runtime.h>

#define TSEQ  784
#define BATCH 256
#define HID   256
#define DNS   1024
#define NCLS  10

__device__ __forceinline__ float sigmoidf_(float x) {
    return 1.0f / (1.0f + __expf(-x));
}
__device__ __forceinline__ float tanhf_(float x) {
    float ax = fabsf(x);
    float e  = __expf(2.0f * ax);
    float r  = 1.0f - 2.0f / (e + 1.0f);
    return copysignf(r, x);
}
__device__ __forceinline__ float4 fma4(float s, float4 w, float4 a) {
    a.x = fmaf(s, w.x, a.x); a.y = fmaf(s, w.y, a.y);
    a.z = fmaf(s, w.z, a.z); a.w = fmaf(s, w.w, a.w);
    return a;
}
__device__ __forceinline__ float4 add4(float4 a, float4 b) {
    return make_float4(a.x + b.x, a.y + b.y, a.z + b.z, a.w + b.w);
}

// One block per batch row. 1024 threads = 4 k-segments x 256 units.
// Entire Wh (1 MB) replicated into the block's registers (256 VGPR/thread).
// h_t lives in LDS; zero cross-block traffic for the whole recurrence.
__global__ __launch_bounds__(1024)
void lstm_row(const float* __restrict__ X,
              const float* __restrict__ W_lstm,
              const float* __restrict__ b_lstm,
              float* __restrict__ h_out)
{
    __shared__ __align__(16) float  hs[HID];
    __shared__ __align__(16) float4 part[1024];   // 16 KB k-split partials

    const int tid = threadIdx.x;
    const int u   = tid & 255;      // unit (gate column within each gate block)
    const int ks  = tid >> 8;       // 0..3 k-segment
    const int b   = blockIdx.x;

    // ---- one-time: weights into registers. wv[kk] = (Wi,Wj,Wf,Wo)[k=ks*64+kk][u]
    float4 wv[64];
    #pragma unroll
    for (int kk = 0; kk < 64; ++kk) {
        const float* wr = W_lstm + (1 + ks * 64 + kk) * 1024 + u;  // row 1+k of W_lstm
        wv[kk].x = wr[0];
        wv[kk].y = wr[256];
        wv[kk].z = wr[512];
        wv[kk].w = wr[768];
    }

    // x-projection weights (row 0) + bias, only for the 256 eltwise threads
    float4 wx = make_float4(0, 0, 0, 0), bb = wx;
    if (tid < 256) {
        const float* wr = W_lstm + u;
        wx.x = wr[0];   wx.y = wr[256];   wx.z = wr[512];   wx.w = wr[768];
        bb.x = b_lstm[u]; bb.y = b_lstm[256 + u]; bb.z = b_lstm[512 + u]; bb.w = b_lstm[768 + u];
        hs[u] = 0.0f;   // h_0 = 0
    }
    const float* xrow = X + b * TSEQ;
    float c = 0.0f, hval = 0.0f;

    __syncthreads();

    for (int t = 0; t < TSEQ; ++t) {
        // ---- phase 1: partial gates over this thread's 64 k's (h reads are wave-broadcast)
        float4 acc = make_float4(0, 0, 0, 0);
        #pragma unroll
        for (int kk = 0; kk < 64; kk += 4) {
            float4 h4 = *reinterpret_cast<const float4*>(&hs[ks * 64 + kk]);
            acc = fma4(h4.x, wv[kk    ], acc);
            acc = fma4(h4.y, wv[kk + 1], acc);
            acc = fma4(h4.z, wv[kk + 2], acc);
            acc = fma4(h4.w, wv[kk + 3], acc);
        }
        part[tid] = acc;
        __syncthreads();

        // ---- phase 2: reduce 4-way k-split + LSTM cell (256 threads)
        if (tid < 256) {
            float4 g = add4(add4(part[u], part[256 + u]),
                            add4(part[512 + u], part[768 + u]));
            const float xv = xrow[t];
            const float gi = g.x + fmaf(xv, wx.x, bb.x);
            const float gj = g.y + fmaf(xv, wx.y, bb.y);
            const float gf = g.z + fmaf(xv, wx.z, bb.z);
            const float go = g.w + fmaf(xv, wx.w, bb.w);
            c = fmaf(sigmoidf_(gf + 1.0f), c, sigmoidf_(gi) * tanhf_(gj));
            hval = sigmoidf_(go) * tanhf_(c);
            hs[u] = hval;
        }
        __syncthreads();
    }

    if (tid < 256) h_out[b * HID + u] = hval;
}

// One block per batch row: dense = relu(h @ W_dense + b); logits = dense @ W_pred + b
__global__ __launch_bounds__(256, 1)
void head_kernel(const float* __restrict__ h_in,
                 const float* __restrict__ W_dense,
                 const float* __restrict__ b_dense,
                 const float* __restrict__ W_pred,
                 const float* __restrict__ b_pred,
                 float* __restrict__ out) {
    __shared__ float hs[HID];
    __shared__ float ds[DNS];
    __shared__ float red[4];

    const int b = blockIdx.x;
    const int tid = threadIdx.x;

    hs[tid] = h_in[b * HID + tid];
    __syncthreads();

    for (int d = tid; d < DNS; d += 256) {
        float acc = b_dense[d];
        for (int k = 0; k < HID; k += 4) {
            float4 h4 = *reinterpret_cast<const float4*>(&hs[k]);
            acc = fmaf(h4.x, W_dense[(k + 0) * DNS + d], acc);
            acc = fmaf(h4.y, W_dense[(k + 1) * DNS + d], acc);
            acc = fmaf(h4.z, W_dense[(k + 2) * DNS + d], acc);
            acc = fmaf(h4.w, W_dense[(k + 3) * DNS + d], acc);
        }
        ds[d] = fmaxf(acc, 0.0f);
    }
    __syncthreads();

    const int wid = tid >> 6, lane = tid & 63;
    for (int c = 0; c < NCLS; ++c) {
        float p = 0.0f;
        for (int k = tid; k < DNS; k += 256) {
            p = fmaf(ds[k], W_pred[k * NCLS + c], p);
        }
        #pragma unroll
        for (int off = 32; off > 0; off >>= 1) {
            p += __shfl_down(p, off, 64);
        }
        if (lane == 0) red[wid] = p;
        __syncthreads();
        if (tid == 0) {
            out[b * NCLS + c] = red[0] + red[1] + red[2] + red[3] + b_pred[c];
        }
        __syncthreads();
    }
}

extern "C" void kernel_launch(void* const* d_in, const int* in_sizes, int n_in,
                              void* d_out, int out_size, void* d_ws, size_t ws_size,
                              hipStream_t stream) {
    const float* X       = (const float*)d_in[0];
    const float* W_lstm  = (const float*)d_in[1];
    const float* b_lstm  = (const float*)d_in[2];
    const float* W_dense = (const float*)d_in[3];
    const float* b_dense = (const float*)d_in[4];
    const float* W_pred  = (const float*)d_in[5];
    const float* b_pred  = (const float*)d_in[6];
    float* out = (float*)d_out;

    float* h_final = (float*)d_ws;   // 256*256 floats

    lstm_row<<<BATCH, 1024, 0, stream>>>(X, W_lstm, b_lstm, h_final);
    head_kernel<<<BATCH, 256, 0, stream>>>(h_final, W_dense, b_dense, W_pred, b_pred, out);
}

// Round 5
// 9212.241 us; speedup vs baseline: 2.3285x; 2.3285x over previous
//
#include <hip/hip_runtime.h>

#define TSEQ  784
#define BATCH 256
#define HID   256
#define DNS   1024
#define NCLS  10
#define NGRP  64    // groups of 4 blocks; each group owns 4 batch rows
#define RPG   4

__device__ __forceinline__ float sigmoidf_(float x) {
    return 1.0f / (1.0f + __expf(-x));
}
__device__ __forceinline__ float tanhf_(float x) {
    float ax = fabsf(x);
    float e  = __expf(2.0f * ax);
    float r  = 1.0f - 2.0f / (e + 1.0f);
    return copysignf(r, x);
}
__device__ __forceinline__ float4 fma4(float s, float4 w, float4 a) {
    a.x = fmaf(s, w.x, a.x); a.y = fmaf(s, w.y, a.y);
    a.z = fmaf(s, w.z, a.z); a.w = fmaf(s, w.w, a.w);
    return a;
}
__device__ __forceinline__ float4 add4(float4 a, float4 b) {
    return make_float4(a.x + b.x, a.y + b.y, a.z + b.z, a.w + b.w);
}
__device__ __forceinline__ float4 shfl_xor4(float4 v, int m) {
    float4 r;
    r.x = __shfl_xor(v.x, m, 64);
    r.y = __shfl_xor(v.y, m, 64);
    r.z = __shfl_xor(v.z, m, 64);
    r.w = __shfl_xor(v.w, m, 64);
    return r;
}

// 256 blocks = 64 groups x 4 unit-slices. Block: 1024 thr = 64 units x 16 k-seg.
// Weight slice (64 units x 256 k x 4 gates = 256 KB) lives in REGISTERS
// (16 float4/thread = 64 VGPR). h_t in LDS (XOR-swizzled), X pre-staged in LDS.
// Cross-block exchange: relaxed-atomic h slices + per-group counter, 2 barriers.
__global__ __launch_bounds__(1024)
void lstm_grp(const float* __restrict__ X,
              const float* __restrict__ W_lstm,
              const float* __restrict__ b_lstm,
              float* __restrict__ hbuf,        // 2 * NGRP * RPG * HID floats
              unsigned int* __restrict__ cnt)  // NGRP counters (monotonic)
{
    __shared__ __align__(16) float hs[RPG * HID];   // 4 KB, f4-swizzled j^(j>>3)
    __shared__ float Xs[RPG * TSEQ];                // 12.25 KB

    const int tid = threadIdx.x;
    const int u   = tid >> 4;     // 0..63 unit within slice
    const int ks  = tid & 15;     // 0..15 k-segment (16 k each)

    const int bid   = blockIdx.x;
    const int x     = bid & 7;            // XCD (empirical round-robin)
    const int m     = bid >> 3;           // 0..31 slot on XCD
    const int g     = x * 8 + (m & 7);    // group 0..63 (members share bid&7)
    const int slice = m >> 3;             // 0..3 unit slice
    const int ubase = slice * 64;
    const int rbase = g * RPG;

    // ---- one-time: weight slice into registers ----
    float4 wv[16];
    #pragma unroll
    for (int kk = 0; kk < 16; ++kk) {
        const float* wr = W_lstm + (1 + ks * 16 + kk) * 1024 + ubase + u;
        wv[kk] = make_float4(wr[0], wr[256], wr[512], wr[768]);
    }
    const float* wr0 = W_lstm + ubase + u;
    float4 wx = make_float4(wr0[0], wr0[256], wr0[512], wr0[768]);
    float4 bb = make_float4(b_lstm[ubase + u], b_lstm[256 + ubase + u],
                            b_lstm[512 + ubase + u], b_lstm[768 + ubase + u]);

    for (int i = tid; i < RPG * TSEQ; i += 1024) {
        const int r = i / TSEQ;
        Xs[i] = X[(rbase + r) * TSEQ + (i - r * TSEQ)];
    }
    for (int i = tid; i < RPG * HID; i += 1024) hs[i] = 0.0f;   // h_0 = 0

    // per-thread swizzled hs read offsets: j = ks*4+q, off = (j ^ (j>>3))*4
    int ro0, ro1, ro2, ro3;
    { int j0 = ks * 4 + 0, j1 = ks * 4 + 1, j2 = ks * 4 + 2, j3 = ks * 4 + 3;
      ro0 = (j0 ^ (j0 >> 3)) << 2; ro1 = (j1 ^ (j1 >> 3)) << 2;
      ro2 = (j2 ^ (j2 >> 3)) << 2; ro3 = (j3 ^ (j3 >> 3)) << 2; }

    const int row = ks >> 2;    // this thread's eltwise row (4-way redundant)
    float c = 0.0f;

    __syncthreads();

    for (int t = 0; t < TSEQ; ++t) {
        // ---- phase 1: acc[r] += h[r][k] * w[k]  (k in my 16-segment) ----
        float4 a0 = make_float4(0, 0, 0, 0), a1 = a0, a2 = a0, a3 = a0;

        #define QSTEP(RO, KK) { \
            float4 h0 = *reinterpret_cast<const float4*>(&hs[0 * 256 + (RO)]); \
            float4 h1 = *reinterpret_cast<const float4*>(&hs[1 * 256 + (RO)]); \
            float4 h2 = *reinterpret_cast<const float4*>(&hs[2 * 256 + (RO)]); \
            float4 h3 = *reinterpret_cast<const float4*>(&hs[3 * 256 + (RO)]); \
            a0 = fma4(h0.x, wv[(KK)], a0);     a1 = fma4(h1.x, wv[(KK)], a1); \
            a2 = fma4(h2.x, wv[(KK)], a2);     a3 = fma4(h3.x, wv[(KK)], a3); \
            a0 = fma4(h0.y, wv[(KK) + 1], a0); a1 = fma4(h1.y, wv[(KK) + 1], a1); \
            a2 = fma4(h2.y, wv[(KK) + 1], a2); a3 = fma4(h3.y, wv[(KK) + 1], a3); \
            a0 = fma4(h0.z, wv[(KK) + 2], a0); a1 = fma4(h1.z, wv[(KK) + 2], a1); \
            a2 = fma4(h2.z, wv[(KK) + 2], a2); a3 = fma4(h3.z, wv[(KK) + 2], a3); \
            a0 = fma4(h0.w, wv[(KK) + 3], a0); a1 = fma4(h1.w, wv[(KK) + 3], a1); \
            a2 = fma4(h2.w, wv[(KK) + 3], a2); a3 = fma4(h3.w, wv[(KK) + 3], a3); }

        QSTEP(ro0, 0) QSTEP(ro1, 4) QSTEP(ro2, 8) QSTEP(ro3, 12)
        #undef QSTEP

        // ---- reduce-scatter 16 ks-lanes -> lane ks holds row ks>>2 ----
        const bool hb8 = (ks & 8) != 0;
        float4 rA = add4(hb8 ? a2 : a0, shfl_xor4(hb8 ? a0 : a2, 8)); // row hb8?2:0
        float4 rB = add4(hb8 ? a3 : a1, shfl_xor4(hb8 ? a1 : a3, 8)); // row hb8?3:1
        const bool hb4 = (ks & 4) != 0;
        float4 rr = add4(hb4 ? rB : rA, shfl_xor4(hb4 ? rA : rB, 4)); // row ks>>2
        rr = add4(rr, shfl_xor4(rr, 2));
        rr = add4(rr, shfl_xor4(rr, 1));

        // ---- eltwise LSTM cell for (row, ubase+u), 4-way redundant ----
        const float xv = Xs[row * TSEQ + t];
        const float gi = rr.x + fmaf(xv, wx.x, bb.x);
        const float gj = rr.y + fmaf(xv, wx.y, bb.y);
        const float gf = rr.z + fmaf(xv, wx.z, bb.z);
        const float go = rr.w + fmaf(xv, wx.w, bb.w);
        c = fmaf(sigmoidf_(gf + 1.0f), c, sigmoidf_(gi) * tanhf_(gj));
        const float hval = sigmoidf_(go) * tanhf_(c);

        const int nb = (t + 1) & 1;
        float* hb = hbuf + (nb * NGRP + g) * (RPG * HID);
        if ((ks & 3) == 0) {
            __hip_atomic_store(&hb[row * HID + ubase + u], hval,
                               __ATOMIC_RELAXED, __HIP_MEMORY_SCOPE_AGENT);
        }

        if (t + 1 < TSEQ) {
            __syncthreads();   // compiler drains vmcnt(0) before s_barrier: stores visible
            if (tid == 0) {
                __hip_atomic_fetch_add(&cnt[g], 1u, __ATOMIC_RELAXED, __HIP_MEMORY_SCOPE_AGENT);
            }
            // all threads poll (no broadcast barrier needed)
            const unsigned int tgt = 4u * (unsigned int)(t + 1);
            int guard = 1 << 22;
            while (__hip_atomic_load(&cnt[g], __ATOMIC_RELAXED, __HIP_MEMORY_SCOPE_AGENT) < tgt) {
                if (--guard == 0) break;   // bounded: never hang
                __builtin_amdgcn_s_sleep(1);
            }
            // reload full group h (1024 floats, 1/thread) into swizzled hs
            const int rr2 = tid >> 8;
            const int k   = tid & 255;
            const float hv = __hip_atomic_load(&hb[rr2 * HID + k],
                                               __ATOMIC_RELAXED, __HIP_MEMORY_SCOPE_AGENT);
            const int j = k >> 2;
            hs[rr2 * 256 + ((j ^ (j >> 3)) << 2) + (k & 3)] = hv;
            __syncthreads();
        }
    }
    // final h (t=784, even) already stored to hbuf buffer 0 in global-row layout
}

// One block per batch row: dense = relu(h @ W_dense + b); logits = dense @ W_pred + b
__global__ __launch_bounds__(256, 1)
void head_kernel(const float* __restrict__ h_in,
                 const float* __restrict__ W_dense,
                 const float* __restrict__ b_dense,
                 const float* __restrict__ W_pred,
                 const float* __restrict__ b_pred,
                 float* __restrict__ out) {
    __shared__ float hs[HID];
    __shared__ float ds[DNS];
    __shared__ float red[4];

    const int b = blockIdx.x;
    const int tid = threadIdx.x;

    hs[tid] = __hip_atomic_load(&h_in[b * HID + tid], __ATOMIC_RELAXED, __HIP_MEMORY_SCOPE_AGENT);
    __syncthreads();

    for (int d = tid; d < DNS; d += 256) {
        float acc = b_dense[d];
        for (int k = 0; k < HID; k += 4) {
            float4 h4 = *reinterpret_cast<const float4*>(&hs[k]);
            acc = fmaf(h4.x, W_dense[(k + 0) * DNS + d], acc);
            acc = fmaf(h4.y, W_dense[(k + 1) * DNS + d], acc);
            acc = fmaf(h4.z, W_dense[(k + 2) * DNS + d], acc);
            acc = fmaf(h4.w, W_dense[(k + 3) * DNS + d], acc);
        }
        ds[d] = fmaxf(acc, 0.0f);
    }
    __syncthreads();

    const int wid = tid >> 6, lane = tid & 63;
    for (int c = 0; c < NCLS; ++c) {
        float p = 0.0f;
        for (int k = tid; k < DNS; k += 256) {
            p = fmaf(ds[k], W_pred[k * NCLS + c], p);
        }
        #pragma unroll
        for (int off = 32; off > 0; off >>= 1) {
            p += __shfl_down(p, off, 64);
        }
        if (lane == 0) red[wid] = p;
        __syncthreads();
        if (tid == 0) {
            out[b * NCLS + c] = red[0] + red[1] + red[2] + red[3] + b_pred[c];
        }
        __syncthreads();
    }
}

extern "C" void kernel_launch(void* const* d_in, const int* in_sizes, int n_in,
                              void* d_out, int out_size, void* d_ws, size_t ws_size,
                              hipStream_t stream) {
    const float* X       = (const float*)d_in[0];
    const float* W_lstm  = (const float*)d_in[1];
    const float* b_lstm  = (const float*)d_in[2];
    const float* W_dense = (const float*)d_in[3];
    const float* b_dense = (const float*)d_in[4];
    const float* W_pred  = (const float*)d_in[5];
    const float* b_pred  = (const float*)d_in[6];
    float* out = (float*)d_out;

    float* hbuf = (float*)d_ws;  // 2 * 64*4*256 floats = 512 KB
    unsigned int* cnt = (unsigned int*)((char*)d_ws + 2 * NGRP * RPG * HID * sizeof(float));

    hipMemsetAsync(cnt, 0, NGRP * sizeof(unsigned int), stream);
    lstm_grp<<<NGRP * 4, 1024, 0, stream>>>(X, W_lstm, b_lstm, hbuf, cnt);
    // h_784 lands in buffer 0 == global-row-major h
    head_kernel<<<BATCH, 256, 0, stream>>>(hbuf, W_dense, b_dense, W_pred, b_pred, out);
}

// Round 6
// 7814.545 us; speedup vs baseline: 2.7449x; 1.1789x over previous
//
#include <hip/hip_runtime.h>

#define TSEQ  784
#define BATCH 256
#define HID   256
#define DNS   1024
#define NCLS  10
#define NGRP  64    // groups of 4 blocks; each group owns 4 batch rows
#define RPG   4

__device__ __forceinline__ float sigmoidf_(float x) {
    return 1.0f / (1.0f + __expf(-x));
}
__device__ __forceinline__ float tanhf_(float x) {
    float ax = fabsf(x);
    float e  = __expf(2.0f * ax);
    float r  = 1.0f - 2.0f / (e + 1.0f);
    return copysignf(r, x);
}
__device__ __forceinline__ float4 fma4(float s, float4 w, float4 a) {
    a.x = fmaf(s, w.x, a.x); a.y = fmaf(s, w.y, a.y);
    a.z = fmaf(s, w.z, a.z); a.w = fmaf(s, w.w, a.w);
    return a;
}
__device__ __forceinline__ float4 add4(float4 a, float4 b) {
    return make_float4(a.x + b.x, a.y + b.y, a.z + b.z, a.w + b.w);
}
__device__ __forceinline__ float4 shfl_xor4(float4 v, int m) {
    float4 r;
    r.x = __shfl_xor(v.x, m, 64);
    r.y = __shfl_xor(v.y, m, 64);
    r.z = __shfl_xor(v.z, m, 64);
    r.w = __shfl_xor(v.w, m, 64);
    return r;
}

// 256 blocks = 64 groups x 4 unit-slices. Block: 512 thr = 64 units x 8 k-seg.
// __launch_bounds__(512, 2): 2 waves/SIMD -> 256-VGPR budget so the 32-float4
// weight slice (128 VGPR/thread, 256 KB/block) STAYS IN REGISTERS.
// h_t in XOR-swizzled LDS; 8-lane butterfly reduce; same-XCD group exchange
// via relaxed-atomic h slices + per-group monotonic counter.
__global__ __launch_bounds__(512, 2)
void lstm_grp(const float* __restrict__ X,
              const float* __restrict__ W_lstm,
              const float* __restrict__ b_lstm,
              float* __restrict__ hbuf,        // 2 * NGRP * RPG * HID floats
              unsigned int* __restrict__ cnt)  // NGRP counters (monotonic)
{
    __shared__ __align__(16) float hs[RPG * HID];   // 4 KB, f4 j stored at j^(j>>3)
    __shared__ float Xs[RPG * TSEQ];                // 12.25 KB

    const int tid = threadIdx.x;
    const int u   = tid >> 3;     // 0..63 unit within slice
    const int ks  = tid & 7;      // 0..7 k-segment (32 k each); lane = (u&7)*8+ks

    const int bid   = blockIdx.x;
    const int slice = bid >> 6;            // 0..3 unit slice
    const int g     = bid & 63;            // group; members share bid%8 = g%8 -> same XCD
    const int ubase = slice * 64;
    const int rbase = g * RPG;

    // ---- one-time: weight slice into registers (128 VGPRs) ----
    float4 wv[32];
    #pragma unroll
    for (int kk = 0; kk < 32; ++kk) {
        const float* wr = W_lstm + (1 + ks * 32 + kk) * 1024 + ubase + u;
        wv[kk] = make_float4(wr[0], wr[256], wr[512], wr[768]);
    }
    const float* wr0 = W_lstm + ubase + u;
    float4 wx = make_float4(wr0[0], wr0[256], wr0[512], wr0[768]);
    float4 bb = make_float4(b_lstm[ubase + u], b_lstm[256 + ubase + u],
                            b_lstm[512 + ubase + u], b_lstm[768 + ubase + u]);

    for (int i = tid; i < RPG * TSEQ; i += 512) {
        const int r = i / TSEQ;
        Xs[i] = X[(rbase + r) * TSEQ + (i - r * TSEQ)];
    }
    for (int i = tid; i < RPG * HID; i += 512) hs[i] = 0.0f;   // h_0 = 0

    const int row = ks >> 1;    // this thread's eltwise row (pair-redundant)
    float c = 0.0f;

    __syncthreads();

    for (int t = 0; t < TSEQ; ++t) {
        // ---- phase 1: acc[r] += h[r][k] * w[k], k in my 32-segment ----
        float4 a0 = make_float4(0, 0, 0, 0), a1 = a0, a2 = a0, a3 = a0;

        #pragma unroll
        for (int q = 0; q < 8; ++q) {
            // f4 index j = ks*8+q, stored at j^(j>>3) = ks*8 + (q^ks)
            const float* hp = &hs[(ks * 8 + (q ^ ks)) << 2];
            float4 h0 = *reinterpret_cast<const float4*>(hp);
            float4 h1 = *reinterpret_cast<const float4*>(hp + 256);
            float4 h2 = *reinterpret_cast<const float4*>(hp + 512);
            float4 h3 = *reinterpret_cast<const float4*>(hp + 768);
            a0 = fma4(h0.x, wv[q * 4 + 0], a0); a0 = fma4(h0.y, wv[q * 4 + 1], a0);
            a0 = fma4(h0.z, wv[q * 4 + 2], a0); a0 = fma4(h0.w, wv[q * 4 + 3], a0);
            a1 = fma4(h1.x, wv[q * 4 + 0], a1); a1 = fma4(h1.y, wv[q * 4 + 1], a1);
            a1 = fma4(h1.z, wv[q * 4 + 2], a1); a1 = fma4(h1.w, wv[q * 4 + 3], a1);
            a2 = fma4(h2.x, wv[q * 4 + 0], a2); a2 = fma4(h2.y, wv[q * 4 + 1], a2);
            a2 = fma4(h2.z, wv[q * 4 + 2], a2); a2 = fma4(h2.w, wv[q * 4 + 3], a2);
            a3 = fma4(h3.x, wv[q * 4 + 0], a3); a3 = fma4(h3.y, wv[q * 4 + 1], a3);
            a3 = fma4(h3.z, wv[q * 4 + 2], a3); a3 = fma4(h3.w, wv[q * 4 + 3], a3);
        }

        // ---- reduce-scatter over 8 ks-lanes -> lane ks holds row ks>>1 ----
        const bool p4 = (ks & 4) != 0;
        float4 rA = add4(p4 ? a2 : a0, shfl_xor4(p4 ? a0 : a2, 4)); // rows 0/2
        float4 rB = add4(p4 ? a3 : a1, shfl_xor4(p4 ? a1 : a3, 4)); // rows 1/3
        const bool p2 = (ks & 2) != 0;
        float4 rr = add4(p2 ? rB : rA, shfl_xor4(p2 ? rA : rB, 2)); // row ks>>1
        rr = add4(rr, shfl_xor4(rr, 1));

        // ---- eltwise LSTM cell for (row, ubase+u), pair-redundant ----
        const float xv = Xs[row * TSEQ + t];
        const float gi = rr.x + fmaf(xv, wx.x, bb.x);
        const float gj = rr.y + fmaf(xv, wx.y, bb.y);
        const float gf = rr.z + fmaf(xv, wx.z, bb.z);
        const float go = rr.w + fmaf(xv, wx.w, bb.w);
        c = fmaf(sigmoidf_(gf + 1.0f), c, sigmoidf_(gi) * tanhf_(gj));
        const float hval = sigmoidf_(go) * tanhf_(c);

        const int nb = (t + 1) & 1;
        float* hb = hbuf + (nb * NGRP + g) * (RPG * HID);
        if ((ks & 1) == 0) {
            __hip_atomic_store(&hb[row * HID + ubase + u], hval,
                               __ATOMIC_RELAXED, __HIP_MEMORY_SCOPE_AGENT);
        }

        if (t + 1 < TSEQ) {
            __syncthreads();   // compiler drains vmcnt(0) before s_barrier: stores visible
            if (tid == 0) {
                __hip_atomic_fetch_add(&cnt[g], 1u, __ATOMIC_RELAXED, __HIP_MEMORY_SCOPE_AGENT);
            }
            const unsigned int tgt = 4u * (unsigned int)(t + 1);
            int guard = 1 << 22;
            while (__hip_atomic_load(&cnt[g], __ATOMIC_RELAXED, __HIP_MEMORY_SCOPE_AGENT) < tgt) {
                if (--guard == 0) break;   // bounded: never hang
                __builtin_amdgcn_s_sleep(1);
            }
            // reload group h (1024 floats, 2/thread, coalesced) into swizzled hs
            const int r2 = tid >> 7;          // 0..3
            const int k0 = (tid & 127) * 2;   // even
            const float v0 = __hip_atomic_load(&hb[r2 * HID + k0],
                                               __ATOMIC_RELAXED, __HIP_MEMORY_SCOPE_AGENT);
            const float v1 = __hip_atomic_load(&hb[r2 * HID + k0 + 1],
                                               __ATOMIC_RELAXED, __HIP_MEMORY_SCOPE_AGENT);
            const int j  = k0 >> 2;
            const int sw = ((j ^ (j >> 3)) << 2) + (k0 & 3);
            hs[r2 * 256 + sw]     = v0;
            hs[r2 * 256 + sw + 1] = v1;
            __syncthreads();
        }
    }
    // final h (t=784, even) already in hbuf buffer 0, global row-major
}

// One block per batch row: dense = relu(h @ W_dense + b); logits = dense @ W_pred + b
__global__ __launch_bounds__(256, 1)
void head_kernel(const float* __restrict__ h_in,
                 const float* __restrict__ W_dense,
                 const float* __restrict__ b_dense,
                 const float* __restrict__ W_pred,
                 const float* __restrict__ b_pred,
                 float* __restrict__ out) {
    __shared__ float hs[HID];
    __shared__ float ds[DNS];
    __shared__ float red[4];

    const int b = blockIdx.x;
    const int tid = threadIdx.x;

    hs[tid] = __hip_atomic_load(&h_in[b * HID + tid], __ATOMIC_RELAXED, __HIP_MEMORY_SCOPE_AGENT);
    __syncthreads();

    for (int d = tid; d < DNS; d += 256) {
        float acc = b_dense[d];
        for (int k = 0; k < HID; k += 4) {
            float4 h4 = *reinterpret_cast<const float4*>(&hs[k]);
            acc = fmaf(h4.x, W_dense[(k + 0) * DNS + d], acc);
            acc = fmaf(h4.y, W_dense[(k + 1) * DNS + d], acc);
            acc = fmaf(h4.z, W_dense[(k + 2) * DNS + d], acc);
            acc = fmaf(h4.w, W_dense[(k + 3) * DNS + d], acc);
        }
        ds[d] = fmaxf(acc, 0.0f);
    }
    __syncthreads();

    const int wid = tid >> 6, lane = tid & 63;
    for (int c = 0; c < NCLS; ++c) {
        float p = 0.0f;
        for (int k = tid; k < DNS; k += 256) {
            p = fmaf(ds[k], W_pred[k * NCLS + c], p);
        }
        #pragma unroll
        for (int off = 32; off > 0; off >>= 1) {
            p += __shfl_down(p, off, 64);
        }
        if (lane == 0) red[wid] = p;
        __syncthreads();
        if (tid == 0) {
            out[b * NCLS + c] = red[0] + red[1] + red[2] + red[3] + b_pred[c];
        }
        __syncthreads();
    }
}

extern "C" void kernel_launch(void* const* d_in, const int* in_sizes, int n_in,
                              void* d_out, int out_size, void* d_ws, size_t ws_size,
                              hipStream_t stream) {
    const float* X       = (const float*)d_in[0];
    const float* W_lstm  = (const float*)d_in[1];
    const float* b_lstm  = (const float*)d_in[2];
    const float* W_dense = (const float*)d_in[3];
    const float* b_dense = (const float*)d_in[4];
    const float* W_pred  = (const float*)d_in[5];
    const float* b_pred  = (const float*)d_in[6];
    float* out = (float*)d_out;

    float* hbuf = (float*)d_ws;  // 2 * 64*4*256 floats = 512 KB
    unsigned int* cnt = (unsigned int*)((char*)d_ws + 2 * NGRP * RPG * HID * sizeof(float));

    hipMemsetAsync(cnt, 0, NGRP * sizeof(unsigned int), stream);
    lstm_grp<<<NGRP * 4, 512, 0, stream>>>(X, W_lstm, b_lstm, hbuf, cnt);
    // h_784 lands in buffer 0 == global-row-major h
    head_kernel<<<BATCH, 256, 0, stream>>>(hbuf, W_dense, b_dense, W_pred, b_pred, out);
}

// Round 7
// 7671.795 us; speedup vs baseline: 2.7960x; 1.0186x over previous
//
#include <hip/hip_runtime.h>

#define TSEQ  784
#define BATCH 256
#define HID   256
#define DNS   1024
#define NCLS  10
#define NGRP  64    // groups of 4 blocks; each group owns 4 batch rows
#define RPG   4

__device__ __forceinline__ float sigmoidf_(float x) {
    return 1.0f / (1.0f + __expf(-x));
}
__device__ __forceinline__ float tanhf_(float x) {
    float ax = fabsf(x);
    float e  = __expf(2.0f * ax);
    float r  = 1.0f - 2.0f / (e + 1.0f);
    return copysignf(r, x);
}
__device__ __forceinline__ float4 fma4(float s, float4 w, float4 a) {
    a.x = fmaf(s, w.x, a.x); a.y = fmaf(s, w.y, a.y);
    a.z = fmaf(s, w.z, a.z); a.w = fmaf(s, w.w, a.w);
    return a;
}
__device__ __forceinline__ float4 add4(float4 a, float4 b) {
    return make_float4(a.x + b.x, a.y + b.y, a.z + b.z, a.w + b.w);
}
__device__ __forceinline__ float4 shfl_xor4(float4 v, int m) {
    float4 r;
    r.x = __shfl_xor(v.x, m, 64);
    r.y = __shfl_xor(v.y, m, 64);
    r.z = __shfl_xor(v.z, m, 64);
    r.w = __shfl_xor(v.w, m, 64);
    return r;
}

// 256 blocks = 64 groups x 4 unit-slices. Block: 512 thr = 64 units x 8 k-seg.
// Weight slice (32 float4/thread = 128 VGPR, 256 KB/block) is PINNED into
// registers via volatile asm (compiler cannot remat/sink pinned values).
// __launch_bounds__(512, 2) -> 256-VGPR budget. h_t in XOR-swizzled LDS;
// 8-lane butterfly reduce; same-XCD group exchange via relaxed atomics.
__global__ __launch_bounds__(512, 2)
void lstm_grp(const float* __restrict__ X,
              const float* __restrict__ W_lstm,
              const float* __restrict__ b_lstm,
              float* __restrict__ hbuf,        // 2 * NGRP * RPG * HID floats
              unsigned int* __restrict__ cnt)  // NGRP counters (monotonic)
{
    __shared__ __align__(16) float hs[RPG * HID];   // 4 KB, f4 j stored at j^(j>>3)
    __shared__ float Xs[RPG * TSEQ];                // 12.25 KB

    const int tid = threadIdx.x;
    const int u   = tid >> 3;     // 0..63 unit within slice
    const int ks  = tid & 7;      // 0..7 k-segment (32 k each)

    const int bid   = blockIdx.x;
    const int slice = bid >> 6;            // 0..3 unit slice
    const int g     = bid & 63;            // group; members share bid%8 -> same XCD
    const int ubase = slice * 64;
    const int rbase = g * RPG;

    // ---- one-time: weight slice into registers (128 VGPRs) ----
    float4 wv[32];
    #pragma unroll
    for (int kk = 0; kk < 32; ++kk) {
        const float* wr = W_lstm + (1 + ks * 32 + kk) * 1024 + ubase + u;
        wv[kk] = make_float4(wr[0], wr[256], wr[512], wr[768]);
    }
    // PIN: volatile asm defines each component; compiler cannot re-execute it,
    // so the weights must stay live in VGPRs for the whole kernel.
    #pragma unroll
    for (int kk = 0; kk < 32; ++kk) {
        asm volatile("" : "+v"(wv[kk].x), "+v"(wv[kk].y), "+v"(wv[kk].z), "+v"(wv[kk].w));
    }

    const float* wr0 = W_lstm + ubase + u;
    float4 wx = make_float4(wr0[0], wr0[256], wr0[512], wr0[768]);
    float4 bb = make_float4(b_lstm[ubase + u], b_lstm[256 + ubase + u],
                            b_lstm[512 + ubase + u], b_lstm[768 + ubase + u]);

    for (int i = tid; i < RPG * TSEQ; i += 512) {
        const int r = i / TSEQ;
        Xs[i] = X[(rbase + r) * TSEQ + (i - r * TSEQ)];
    }
    for (int i = tid; i < RPG * HID; i += 512) hs[i] = 0.0f;   // h_0 = 0

    const int row = ks >> 1;    // this thread's eltwise row (pair-redundant)
    float c = 0.0f;

    __syncthreads();

    for (int t = 0; t < TSEQ; ++t) {
        // ---- phase 1: acc[r] += h[r][k] * w[k], k in my 32-segment ----
        float4 a0 = make_float4(0, 0, 0, 0), a1 = a0, a2 = a0, a3 = a0;

        #pragma unroll
        for (int q = 0; q < 8; ++q) {
            // f4 index j = ks*8+q, stored at j^(j>>3) = ks*8 + (q^ks)
            const float* hp = &hs[(ks * 8 + (q ^ ks)) << 2];
            float4 h0 = *reinterpret_cast<const float4*>(hp);
            float4 h1 = *reinterpret_cast<const float4*>(hp + 256);
            float4 h2 = *reinterpret_cast<const float4*>(hp + 512);
            float4 h3 = *reinterpret_cast<const float4*>(hp + 768);
            a0 = fma4(h0.x, wv[q * 4 + 0], a0); a0 = fma4(h0.y, wv[q * 4 + 1], a0);
            a0 = fma4(h0.z, wv[q * 4 + 2], a0); a0 = fma4(h0.w, wv[q * 4 + 3], a0);
            a1 = fma4(h1.x, wv[q * 4 + 0], a1); a1 = fma4(h1.y, wv[q * 4 + 1], a1);
            a1 = fma4(h1.z, wv[q * 4 + 2], a1); a1 = fma4(h1.w, wv[q * 4 + 3], a1);
            a2 = fma4(h2.x, wv[q * 4 + 0], a2); a2 = fma4(h2.y, wv[q * 4 + 1], a2);
            a2 = fma4(h2.z, wv[q * 4 + 2], a2); a2 = fma4(h2.w, wv[q * 4 + 3], a2);
            a3 = fma4(h3.x, wv[q * 4 + 0], a3); a3 = fma4(h3.y, wv[q * 4 + 1], a3);
            a3 = fma4(h3.z, wv[q * 4 + 2], a3); a3 = fma4(h3.w, wv[q * 4 + 3], a3);
        }

        // ---- reduce-scatter over 8 ks-lanes -> lane ks holds row ks>>1 ----
        const bool p4 = (ks & 4) != 0;
        float4 rA = add4(p4 ? a2 : a0, shfl_xor4(p4 ? a0 : a2, 4)); // rows 0/2
        float4 rB = add4(p4 ? a3 : a1, shfl_xor4(p4 ? a1 : a3, 4)); // rows 1/3
        const bool p2 = (ks & 2) != 0;
        float4 rr = add4(p2 ? rB : rA, shfl_xor4(p2 ? rA : rB, 2)); // row ks>>1
        rr = add4(rr, shfl_xor4(rr, 1));

        // ---- eltwise LSTM cell for (row, ubase+u), pair-redundant ----
        const float xv = Xs[row * TSEQ + t];
        const float gi = rr.x + fmaf(xv, wx.x, bb.x);
        const float gj = rr.y + fmaf(xv, wx.y, bb.y);
        const float gf = rr.z + fmaf(xv, wx.z, bb.z);
        const float go = rr.w + fmaf(xv, wx.w, bb.w);
        c = fmaf(sigmoidf_(gf + 1.0f), c, sigmoidf_(gi) * tanhf_(gj));
        const float hval = sigmoidf_(go) * tanhf_(c);

        const int nb = (t + 1) & 1;
        float* hb = hbuf + (nb * NGRP + g) * (RPG * HID);
        if ((ks & 1) == 0) {
            __hip_atomic_store(&hb[row * HID + ubase + u], hval,
                               __ATOMIC_RELAXED, __HIP_MEMORY_SCOPE_AGENT);
        }

        if (t + 1 < TSEQ) {
            __syncthreads();   // compiler drains vmcnt(0) before s_barrier: stores visible
            if (tid == 0) {
                __hip_atomic_fetch_add(&cnt[g], 1u, __ATOMIC_RELAXED, __HIP_MEMORY_SCOPE_AGENT);
            }
            const unsigned int tgt = 4u * (unsigned int)(t + 1);
            int guard = 1 << 22;
            while (__hip_atomic_load(&cnt[g], __ATOMIC_RELAXED, __HIP_MEMORY_SCOPE_AGENT) < tgt) {
                if (--guard == 0) break;   // bounded: never hang
                __builtin_amdgcn_s_sleep(1);
            }
            // reload group h (1024 floats, 2/thread, coalesced) into swizzled hs
            const int r2 = tid >> 7;          // 0..3
            const int k0 = (tid & 127) * 2;   // even
            const float v0 = __hip_atomic_load(&hb[r2 * HID + k0],
                                               __ATOMIC_RELAXED, __HIP_MEMORY_SCOPE_AGENT);
            const float v1 = __hip_atomic_load(&hb[r2 * HID + k0 + 1],
                                               __ATOMIC_RELAXED, __HIP_MEMORY_SCOPE_AGENT);
            const int j  = k0 >> 2;
            const int sw = ((j ^ (j >> 3)) << 2) + (k0 & 3);
            hs[r2 * 256 + sw]     = v0;
            hs[r2 * 256 + sw + 1] = v1;
            __syncthreads();
        }
    }
    // final h (t=784, even) already in hbuf buffer 0, global row-major
}

// One block per batch row: dense = relu(h @ W_dense + b); logits = dense @ W_pred + b
__global__ __launch_bounds__(256, 1)
void head_kernel(const float* __restrict__ h_in,
                 const float* __restrict__ W_dense,
                 const float* __restrict__ b_dense,
                 const float* __restrict__ W_pred,
                 const float* __restrict__ b_pred,
                 float* __restrict__ out) {
    __shared__ float hs[HID];
    __shared__ float ds[DNS];
    __shared__ float red[4];

    const int b = blockIdx.x;
    const int tid = threadIdx.x;

    hs[tid] = __hip_atomic_load(&h_in[b * HID + tid], __ATOMIC_RELAXED, __HIP_MEMORY_SCOPE_AGENT);
    __syncthreads();

    for (int d = tid; d < DNS; d += 256) {
        float acc = b_dense[d];
        for (int k = 0; k < HID; k += 4) {
            float4 h4 = *reinterpret_cast<const float4*>(&hs[k]);
            acc = fmaf(h4.x, W_dense[(k + 0) * DNS + d], acc);
            acc = fmaf(h4.y, W_dense[(k + 1) * DNS + d], acc);
            acc = fmaf(h4.z, W_dense[(k + 2) * DNS + d], acc);
            acc = fmaf(h4.w, W_dense[(k + 3) * DNS + d], acc);
        }
        ds[d] = fmaxf(acc, 0.0f);
    }
    __syncthreads();

    const int wid = tid >> 6, lane = tid & 63;
    for (int c = 0; c < NCLS; ++c) {
        float p = 0.0f;
        for (int k = tid; k < DNS; k += 256) {
            p = fmaf(ds[k], W_pred[k * NCLS + c], p);
        }
        #pragma unroll
        for (int off = 32; off > 0; off >>= 1) {
            p += __shfl_down(p, off, 64);
        }
        if (lane == 0) red[wid] = p;
        __syncthreads();
        if (tid == 0) {
            out[b * NCLS + c] = red[0] + red[1] + red[2] + red[3] + b_pred[c];
        }
        __syncthreads();
    }
}

extern "C" void kernel_launch(void* const* d_in, const int* in_sizes, int n_in,
                              void* d_out, int out_size, void* d_ws, size_t ws_size,
                              hipStream_t stream) {
    const float* X       = (const float*)d_in[0];
    const float* W_lstm  = (const float*)d_in[1];
    const float* b_lstm  = (const float*)d_in[2];
    const float* W_dense = (const float*)d_in[3];
    const float* b_dense = (const float*)d_in[4];
    const float* W_pred  = (const float*)d_in[5];
    const float* b_pred  = (const float*)d_in[6];
    float* out = (float*)d_out;

    float* hbuf = (float*)d_ws;  // 2 * 64*4*256 floats = 512 KB
    unsigned int* cnt = (unsigned int*)((char*)d_ws + 2 * NGRP * RPG * HID * sizeof(float));

    hipMemsetAsync(cnt, 0, NGRP * sizeof(unsigned int), stream);
    lstm_grp<<<NGRP * 4, 512, 0, stream>>>(X, W_lstm, b_lstm, hbuf, cnt);
    // h_784 lands in buffer 0 == global-row-major h
    head_kernel<<<BATCH, 256, 0, stream>>>(hbuf, W_dense, b_dense, W_pred, b_pred, out);
}

// Round 8
// 6914.753 us; speedup vs baseline: 3.1021x; 1.1095x over previous
//
#include <hip/hip_runtime.h>
#include <stdint.h>

#define TSEQ  784
#define BATCH 256
#define HID   256
#define DNS   1024
#define NCLS  10
#define NGRP  16   // groups (16 batch rows each)
#define NSLC  8    // slices (32 units x 4 gates = 128 gate-cols each)

typedef __attribute__((ext_vector_type(8))) short bf16x8_t;
typedef __attribute__((ext_vector_type(4))) float f32x4_t;

__device__ __forceinline__ float sigmoidf_(float x) { return 1.0f / (1.0f + __expf(-x)); }
__device__ __forceinline__ float tanhf_(float x) {
    float ax = fabsf(x);
    float e  = __expf(2.0f * ax);
    float r  = 1.0f - 2.0f / (e + 1.0f);
    return copysignf(r, x);
}
__device__ __forceinline__ uint32_t bf16rne(float f) {
    uint32_t u = __float_as_uint(f);
    return (u + 0x7FFFu + ((u >> 16) & 1u)) >> 16;
}
__device__ __forceinline__ float bf16tof(uint32_t h) { return __uint_as_float(h << 16); }

// 128 blocks = 16 groups x 8 slices, 256 threads (4 waves).
// Wh slice in LDS as bf16 hi/lo (128 KB, XOR-swizzled). GEMM = 3-term split MFMA.
// h exchanged via global chunks in A-fragment order (bf16 hi/lo packed dwords),
// agent-relaxed atomics + per-(group,slice) monotonic tags.
__global__ __launch_bounds__(256, 1)
void lstm_mfma(const float* __restrict__ X,
               const float* __restrict__ W_lstm,
               const float* __restrict__ b_lstm,
               uint32_t* __restrict__ hx,      // 2 bufs * 16 g * 8 s * 512 dwords = 512 KB
               uint32_t* __restrict__ tags)    // 128 monotonic tags
{
    __shared__ uint32_t WtU[32768];      // 128 KB: [lvl][n(8)][c(16)][128 dw, chunk-swizzled]
    __shared__ float    gateL[64 * 33];  // 8.4 KB: [(q*16+row)][33] padded

    const int tid  = threadIdx.x;
    const int lane = tid & 63;
    const int wid  = tid >> 6;    // 0..3 == gate q owned by this wave
    const int cidx = lane & 15;   // B col / A row within tile
    const int kh   = lane >> 4;   // 0..3 k-subgroup

    const int bid = blockIdx.x;
    const int s   = bid >> 4;     // slice 0..7
    const int g   = bid & 15;     // group 0..15 (bid%8 = g%8 -> slices of g share an XCD)

    // ---- one-time: stage Wh slice into LDS as bf16 hi/lo, chunk-XOR-swizzled ----
    for (int idx = tid; idx < 8 * 16 * 128; idx += 256) {
        const int n  = idx >> 11;          // n-tile 0..7
        const int c  = (idx >> 7) & 15;    // col within tile
        const int dw = idx & 127;          // k-pair index (k = 2*dw, 2*dw+1)
        const int k0 = dw * 2;
        const int col = (n >> 1) * 256 + s * 32 + (n & 1) * 16 + c;
        const float w0 = W_lstm[(1 + k0) * 1024 + col];
        const float w1 = W_lstm[(2 + k0) * 1024 + col];
        const uint32_t h0 = bf16rne(w0), h1 = bf16rne(w1);
        const uint32_t l0 = bf16rne(w0 - bf16tof(h0));
        const uint32_t l1 = bf16rne(w1 - bf16tof(h1));
        const int kc = dw >> 2, rem = dw & 3;
        const int dwp = ((kc ^ (c & 7)) << 2) | rem;     // 16B-chunk XOR swizzle
        const int o = (n * 16 + c) * 128 + dwp;
        WtU[o]         = h0 | (h1 << 16);
        WtU[16384 + o] = l0 | (l1 << 16);
    }

    // eltwise mapping: thread -> (row er, unit-pair base eu); cells (er,eu),(er,eu+16)
    const int er = tid >> 4;   // 0..15
    const int eu = tid & 15;   // 0..15
    float wx0[4], wx1[4], bb0[4], bb1[4];
    #pragma unroll
    for (int q = 0; q < 4; ++q) {
        const int c0 = q * 256 + s * 32 + eu;
        wx0[q] = W_lstm[c0];      wx1[q] = W_lstm[c0 + 16];
        bb0[q] = b_lstm[c0];      bb1[q] = b_lstm[c0 + 16];
    }
    const float* xrow = X + (g * 16 + er) * TSEQ;
    float cc0 = 0.0f, cc1 = 0.0f;

    __syncthreads();

    for (int t = 0; t < TSEQ; ++t) {
        // ---- wait for h_t: all 8 producer tags >= t ----
        if (t > 0) {
            int guard = 1 << 22;
            bool ok;
            do {
                ok = true;
                #pragma unroll
                for (int ss = 0; ss < 8; ++ss) {
                    uint32_t v = __hip_atomic_load(&tags[g * 8 + ss],
                                                   __ATOMIC_RELAXED, __HIP_MEMORY_SCOPE_AGENT);
                    ok &= (v >= (uint32_t)t);
                }
            } while (!ok && --guard);
        }
        __syncthreads();   // fence: A-loads below cannot hoist above the poll

        // ---- A-fragments (h_t hi/lo) for all 8 k-tiles, straight from global ----
        const int bufr = t & 1;
        union AF { uint32_t u[4]; bf16x8_t v; };
        AF ah[8], al[8];
        #pragma unroll
        for (int kt = 0; kt < 8; ++kt) {
            const int base = ((bufr * NGRP + g) * NSLC + kt) * 512 + cidx * 16 + kh * 4;
            #pragma unroll
            for (int d = 0; d < 4; ++d) {
                ah[kt].u[d] = __hip_atomic_load(&hx[base + d],
                                                __ATOMIC_RELAXED, __HIP_MEMORY_SCOPE_AGENT);
                al[kt].u[d] = __hip_atomic_load(&hx[base + 256 + d],
                                                __ATOMIC_RELAXED, __HIP_MEMORY_SCOPE_AGENT);
            }
        }

        // ---- GEMM: 3-term split, acc over this wave's 2 n-tiles ----
        f32x4_t acc0 = {0.f, 0.f, 0.f, 0.f}, acc1 = acc0;
        #pragma unroll
        for (int kt = 0; kt < 8; ++kt) {
            const int kc = kt * 4 + kh;
            {
                const int ob = ((wid * 2) * 16 + cidx) * 128 + ((kc ^ (cidx & 7)) << 2);
                bf16x8_t bh = *reinterpret_cast<const bf16x8_t*>(&WtU[ob]);
                bf16x8_t bl = *reinterpret_cast<const bf16x8_t*>(&WtU[16384 + ob]);
                acc0 = __builtin_amdgcn_mfma_f32_16x16x32_bf16(ah[kt].v, bh, acc0, 0, 0, 0);
                acc0 = __builtin_amdgcn_mfma_f32_16x16x32_bf16(ah[kt].v, bl, acc0, 0, 0, 0);
                acc0 = __builtin_amdgcn_mfma_f32_16x16x32_bf16(al[kt].v, bh, acc0, 0, 0, 0);
            }
            {
                const int ob = ((wid * 2 + 1) * 16 + cidx) * 128 + ((kc ^ (cidx & 7)) << 2);
                bf16x8_t bh = *reinterpret_cast<const bf16x8_t*>(&WtU[ob]);
                bf16x8_t bl = *reinterpret_cast<const bf16x8_t*>(&WtU[16384 + ob]);
                acc1 = __builtin_amdgcn_mfma_f32_16x16x32_bf16(ah[kt].v, bh, acc1, 0, 0, 0);
                acc1 = __builtin_amdgcn_mfma_f32_16x16x32_bf16(ah[kt].v, bl, acc1, 0, 0, 0);
                acc1 = __builtin_amdgcn_mfma_f32_16x16x32_bf16(al[kt].v, bh, acc1, 0, 0, 0);
            }
        }

        // ---- scatter gates to LDS (D layout: col=lane&15, row=(lane>>4)*4+reg) ----
        #pragma unroll
        for (int reg = 0; reg < 4; ++reg) {
            gateL[(wid * 16 + kh * 4 + reg) * 33 + cidx]      = acc0[reg];
            gateL[(wid * 16 + kh * 4 + reg) * 33 + 16 + cidx] = acc1[reg];
        }
        __syncthreads();

        // ---- eltwise LSTM cell for (er, eu) and (er, eu+16) ----
        const float xv = xrow[t];
        float g0[4], g1[4];
        #pragma unroll
        for (int q = 0; q < 4; ++q) {
            g0[q] = gateL[(q * 16 + er) * 33 + eu]      + xv * wx0[q] + bb0[q];
            g1[q] = gateL[(q * 16 + er) * 33 + 16 + eu] + xv * wx1[q] + bb1[q];
        }
        cc0 = fmaf(sigmoidf_(g0[2] + 1.0f), cc0, sigmoidf_(g0[0]) * tanhf_(g0[1]));
        const float h0 = sigmoidf_(g0[3]) * tanhf_(cc0);
        cc1 = fmaf(sigmoidf_(g1[2] + 1.0f), cc1, sigmoidf_(g1[0]) * tanhf_(g1[1]));
        const float h1 = sigmoidf_(g1[3]) * tanhf_(cc1);

        // ---- pack own h-chunk (A-frag order: dword D = units (2D, 2D+1)) ----
        const float h0n = __shfl_xor(h0, 1, 64);
        const float h1n = __shfl_xor(h1, 1, 64);
        if ((eu & 1) == 0) {
            const int bufw  = (t + 1) & 1;
            const int basew = ((bufw * NGRP + g) * NSLC + s) * 512 + er * 16;
            const uint32_t hi0 = bf16rne(h0),  hi0n = bf16rne(h0n);
            const uint32_t hi1 = bf16rne(h1),  hi1n = bf16rne(h1n);
            const uint32_t lo0  = bf16rne(h0  - bf16tof(hi0));
            const uint32_t lo0n = bf16rne(h0n - bf16tof(hi0n));
            const uint32_t lo1  = bf16rne(h1  - bf16tof(hi1));
            const uint32_t lo1n = bf16rne(h1n - bf16tof(hi1n));
            const int D0 = eu >> 1, D1 = 8 + (eu >> 1);
            __hip_atomic_store(&hx[basew + D0], hi0 | (hi0n << 16),
                               __ATOMIC_RELAXED, __HIP_MEMORY_SCOPE_AGENT);
            __hip_atomic_store(&hx[basew + D1], hi1 | (hi1n << 16),
                               __ATOMIC_RELAXED, __HIP_MEMORY_SCOPE_AGENT);
            __hip_atomic_store(&hx[basew + 256 + D0], lo0 | (lo0n << 16),
                               __ATOMIC_RELAXED, __HIP_MEMORY_SCOPE_AGENT);
            __hip_atomic_store(&hx[basew + 256 + D1], lo1 | (lo1n << 16),
                               __ATOMIC_RELAXED, __HIP_MEMORY_SCOPE_AGENT);
        }
        __syncthreads();   // drains vmcnt(0): chunk stores at coherent point; gateL reusable
        if (tid == 0) {
            __hip_atomic_store(&tags[g * 8 + s], (uint32_t)(t + 1),
                               __ATOMIC_RELAXED, __HIP_MEMORY_SCOPE_AGENT);
        }
    }
    // final h_784 lives in hx buf 0 as bf16 hi/lo; head kernel reconstructs.
}

// One block per batch row: dense = relu(h @ W_dense + b); logits = dense @ W_pred + b
__global__ __launch_bounds__(256, 1)
void head_kernel(const uint32_t* __restrict__ hx,
                 const float* __restrict__ W_dense,
                 const float* __restrict__ b_dense,
                 const float* __restrict__ W_pred,
                 const float* __restrict__ b_pred,
                 float* __restrict__ out) {
    __shared__ float hs[HID];
    __shared__ float ds[DNS];
    __shared__ float red[4];

    const int b = blockIdx.x;
    const int g = b >> 4, er = b & 15;
    const int tid = threadIdx.x;

    {   // reconstruct h = hi + lo from buf 0 chunk of (g, slice s)
        const int s  = tid >> 5;
        const int uu = tid & 31;
        const int base = ((0 * NGRP + g) * NSLC + s) * 512 + er * 16;
        const uint32_t dh = __hip_atomic_load(&hx[base + (uu >> 1)],
                                              __ATOMIC_RELAXED, __HIP_MEMORY_SCOPE_AGENT);
        const uint32_t dl = __hip_atomic_load(&hx[base + 256 + (uu >> 1)],
                                              __ATOMIC_RELAXED, __HIP_MEMORY_SCOPE_AGENT);
        const int sh = (uu & 1) * 16;
        hs[tid] = bf16tof((dh >> sh) & 0xFFFFu) + bf16tof((dl >> sh) & 0xFFFFu);
    }
    __syncthreads();

    for (int d = tid; d < DNS; d += 256) {
        float acc = b_dense[d];
        for (int k = 0; k < HID; k += 4) {
            float4 h4 = *reinterpret_cast<const float4*>(&hs[k]);
            acc = fmaf(h4.x, W_dense[(k + 0) * DNS + d], acc);
            acc = fmaf(h4.y, W_dense[(k + 1) * DNS + d], acc);
            acc = fmaf(h4.z, W_dense[(k + 2) * DNS + d], acc);
            acc = fmaf(h4.w, W_dense[(k + 3) * DNS + d], acc);
        }
        ds[d] = fmaxf(acc, 0.0f);
    }
    __syncthreads();

    const int wid = tid >> 6, lane = tid & 63;
    for (int c = 0; c < NCLS; ++c) {
        float p = 0.0f;
        for (int k = tid; k < DNS; k += 256) {
            p = fmaf(ds[k], W_pred[k * NCLS + c], p);
        }
        #pragma unroll
        for (int off = 32; off > 0; off >>= 1) {
            p += __shfl_down(p, off, 64);
        }
        if (lane == 0) red[wid] = p;
        __syncthreads();
        if (tid == 0) {
            out[b * NCLS + c] = red[0] + red[1] + red[2] + red[3] + b_pred[c];
        }
        __syncthreads();
    }
}

extern "C" void kernel_launch(void* const* d_in, const int* in_sizes, int n_in,
                              void* d_out, int out_size, void* d_ws, size_t ws_size,
                              hipStream_t stream) {
    const float* X       = (const float*)d_in[0];
    const float* W_lstm  = (const float*)d_in[1];
    const float* b_lstm  = (const float*)d_in[2];
    const float* W_dense = (const float*)d_in[3];
    const float* b_dense = (const float*)d_in[4];
    const float* W_pred  = (const float*)d_in[5];
    const float* b_pred  = (const float*)d_in[6];
    float* out = (float*)d_out;

    uint32_t* hx   = (uint32_t*)d_ws;                 // 131072 dwords = 512 KB
    uint32_t* tags = hx + 131072;                     // 128 dwords

    // h_0 = 0 (buf 0) and tags = 0, every launch (graph-replay deterministic)
    hipMemsetAsync(hx, 0, NGRP * NSLC * 512 * sizeof(uint32_t), stream);
    hipMemsetAsync(tags, 0, NGRP * NSLC * sizeof(uint32_t), stream);

    lstm_mfma<<<NGRP * NSLC, 256, 0, stream>>>(X, W_lstm, b_lstm, hx, tags);
    head_kernel<<<BATCH, 256, 0, stream>>>(hx, W_dense, b_dense, W_pred, b_pred, out);
}

// Round 9
// 2224.841 us; speedup vs baseline: 9.6413x; 3.1080x over previous
//
#include <hip/hip_runtime.h>
#include <stdint.h>

#define TSEQ  784
#define BATCH 256
#define HID   256
#define DNS   1024
#define NCLS  10
#define NGRP  16   // groups (16 batch rows each)
#define NSLC  8    // slices (32 units x 4 gates = 128 gate-cols each)

typedef __attribute__((ext_vector_type(8))) short bf16x8_t;
typedef __attribute__((ext_vector_type(4))) float f32x4_t;

__device__ __forceinline__ float sigmoidf_(float x) { return 1.0f / (1.0f + __expf(-x)); }
__device__ __forceinline__ float tanhf_(float x) {
    float ax = fabsf(x);
    float e  = __expf(2.0f * ax);
    float r  = 1.0f - 2.0f / (e + 1.0f);
    return copysignf(r, x);
}
__device__ __forceinline__ uint32_t bf16rne(float f) {
    uint32_t u = __float_as_uint(f);
    return (u + 0x7FFFu + ((u >> 16) & 1u)) >> 16;
}
__device__ __forceinline__ float bf16tof(uint32_t h) { return __uint_as_float(h << 16); }

// 128 blocks = 16 groups x 8 slices, 256 threads (4 waves).
// Wh slice in LDS bf16 hi/lo (128 KB). 3-term split MFMA GEMM.
// Exchange: h chunks in global (A-frag order), staged ONCE per block into
// LDS hA via coalesced uint64 relaxed atomics; single-wave tag poll.
__global__ __launch_bounds__(256, 1)
void lstm_mfma(const float* __restrict__ X,
               const float* __restrict__ W_lstm,
               const float* __restrict__ b_lstm,
               uint32_t* __restrict__ hx,      // 2 bufs * 16 g * 8 s * 512 dwords
               uint32_t* __restrict__ tags)    // 128 monotonic tags
{
    __shared__ uint32_t WtU[32768];           // 128 KB weights bf16 hi/lo, swizzled
    __shared__ uint32_t hA[4096];             // 16 KB h_t (hi/lo), A-frag order, swizzled
    __shared__ float    gateL[4 * 32 * 17];   // 8.5 KB gates [q][col][row+pad]

    const int tid  = threadIdx.x;
    const int lane = tid & 63;
    const int wid  = tid >> 6;    // 0..3 == gate q owned by this wave
    const int cidx = lane & 15;   // B col / A row within tile
    const int kh   = lane >> 4;   // 0..3 k-subgroup

    const int bid = blockIdx.x;
    const int s   = bid >> 4;     // slice 0..7
    const int g   = bid & 15;     // group 0..15

    // ---- one-time: stage Wh slice into LDS as bf16 hi/lo, chunk-XOR-swizzled ----
    for (int idx = tid; idx < 8 * 16 * 128; idx += 256) {
        const int n  = idx >> 11;          // n-tile 0..7
        const int c  = (idx >> 7) & 15;    // col within tile
        const int dw = idx & 127;          // k-pair index
        const int k0 = dw * 2;
        const int col = (n >> 1) * 256 + s * 32 + (n & 1) * 16 + c;
        const float w0 = W_lstm[(1 + k0) * 1024 + col];
        const float w1 = W_lstm[(2 + k0) * 1024 + col];
        const uint32_t h0 = bf16rne(w0), h1 = bf16rne(w1);
        const uint32_t l0 = bf16rne(w0 - bf16tof(h0));
        const uint32_t l1 = bf16rne(w1 - bf16tof(h1));
        const int kc = dw >> 2, rem = dw & 3;
        const int dwp = ((kc ^ (c & 7)) << 2) | rem;
        const int o = (n * 16 + c) * 128 + dwp;
        WtU[o]         = h0 | (h1 << 16);
        WtU[16384 + o] = l0 | (l1 << 16);
    }

    // eltwise mapping: thread -> (row er, unit eu); cells (er,eu),(er,eu+16)
    const int er = tid >> 4;
    const int eu = tid & 15;
    float wx0[4], wx1[4], bb0[4], bb1[4];
    #pragma unroll
    for (int q = 0; q < 4; ++q) {
        const int c0 = q * 256 + s * 32 + eu;
        wx0[q] = W_lstm[c0];      wx1[q] = W_lstm[c0 + 16];
        bb0[q] = b_lstm[c0];      bb1[q] = b_lstm[c0 + 16];
    }
    const float* xrow = X + (g * 16 + er) * TSEQ;
    float cc0 = 0.0f, cc1 = 0.0f;

    const int key = (cidx + (cidx >> 2)) & 3;   // hA read swizzle key
    const int kq  = (kh ^ key) << 2;

    __syncthreads();

    for (int t = 0; t < TSEQ; ++t) {
        // ---- wave 0 polls all 8 producer tags >= t ----
        if (t > 0 && wid == 0) {
            const uint32_t tt = (uint32_t)t;
            int guard = 1 << 22;
            bool ok;
            do {
                uint32_t v = __hip_atomic_load(&tags[g * 8 + (lane & 7)],
                                               __ATOMIC_RELAXED, __HIP_MEMORY_SCOPE_AGENT);
                ok = __all(v >= tt);
            } while (!ok && --guard);
        }
        __syncthreads();   // join + fence: stage loads cannot hoist above poll

        // ---- stage h_t (hi+lo, all 8 chunks = 16 KB) into LDS, coalesced u64 ----
        {
            const int bufr = t & 1;
            const unsigned long long* src =
                (const unsigned long long*)hx + (size_t)(bufr * NGRP + g) * 2048;
            unsigned long long v[8];
            #pragma unroll
            for (int j = 0; j < 8; ++j) {
                v[j] = __hip_atomic_load(&src[j * 256 + tid],
                                         __ATOMIC_RELAXED, __HIP_MEMORY_SCOPE_AGENT);
            }
            #pragma unroll
            for (int j = 0; j < 8; ++j) {
                const int m   = j * 256 + tid;      // u64 index; dword n = 2m
                const int kt  = m >> 8;
                const int lvl = (m >> 7) & 1;
                const int ci  = (m & 127) >> 3;
                const int ko  = (m & 7) * 2;        // even koff
                const int khj = ko >> 2, dp = ko & 3;
                const int kyj = (ci + (ci >> 2)) & 3;
                const int dst = kt * 512 + lvl * 256 + ci * 16 + ((khj ^ kyj) << 2) + dp;
                *(unsigned long long*)&hA[dst] = v[j];
            }
        }
        __syncthreads();

        // ---- GEMM: 3-term split over 8 k-tiles, 2 n-tiles per wave ----
        f32x4_t acc0 = {0.f, 0.f, 0.f, 0.f}, acc1 = acc0;
        #pragma unroll
        for (int kt = 0; kt < 8; ++kt) {
            bf16x8_t av_h = *reinterpret_cast<const bf16x8_t*>(&hA[kt * 512 + cidx * 16 + kq]);
            bf16x8_t av_l = *reinterpret_cast<const bf16x8_t*>(&hA[kt * 512 + 256 + cidx * 16 + kq]);
            const int kc = kt * 4 + kh;
            const int ob0 = ((wid * 2) * 16 + cidx) * 128 + ((kc ^ (cidx & 7)) << 2);
            const int ob1 = ((wid * 2 + 1) * 16 + cidx) * 128 + ((kc ^ (cidx & 7)) << 2);
            bf16x8_t bh0 = *reinterpret_cast<const bf16x8_t*>(&WtU[ob0]);
            bf16x8_t bl0 = *reinterpret_cast<const bf16x8_t*>(&WtU[16384 + ob0]);
            bf16x8_t bh1 = *reinterpret_cast<const bf16x8_t*>(&WtU[ob1]);
            bf16x8_t bl1 = *reinterpret_cast<const bf16x8_t*>(&WtU[16384 + ob1]);
            acc0 = __builtin_amdgcn_mfma_f32_16x16x32_bf16(av_h, bh0, acc0, 0, 0, 0);
            acc0 = __builtin_amdgcn_mfma_f32_16x16x32_bf16(av_h, bl0, acc0, 0, 0, 0);
            acc0 = __builtin_amdgcn_mfma_f32_16x16x32_bf16(av_l, bh0, acc0, 0, 0, 0);
            acc1 = __builtin_amdgcn_mfma_f32_16x16x32_bf16(av_h, bh1, acc1, 0, 0, 0);
            acc1 = __builtin_amdgcn_mfma_f32_16x16x32_bf16(av_h, bl1, acc1, 0, 0, 0);
            acc1 = __builtin_amdgcn_mfma_f32_16x16x32_bf16(av_l, bh1, acc1, 0, 0, 0);
        }

        // ---- scatter gates (D: col=lane&15, row=(lane>>4)*4+reg) to [q][col][17] ----
        #pragma unroll
        for (int reg = 0; reg < 4; ++reg) {
            gateL[(wid * 32 + cidx) * 17      + kh * 4 + reg] = acc0[reg];
            gateL[(wid * 32 + 16 + cidx) * 17 + kh * 4 + reg] = acc1[reg];
        }
        __syncthreads();

        // ---- eltwise LSTM cell for (er, eu) and (er, eu+16) ----
        const float xv = xrow[t];
        float g0[4], g1[4];
        #pragma unroll
        for (int q = 0; q < 4; ++q) {
            g0[q] = gateL[(q * 32 + eu) * 17 + er]      + xv * wx0[q] + bb0[q];
            g1[q] = gateL[(q * 32 + 16 + eu) * 17 + er] + xv * wx1[q] + bb1[q];
        }
        cc0 = fmaf(sigmoidf_(g0[2] + 1.0f), cc0, sigmoidf_(g0[0]) * tanhf_(g0[1]));
        const float h0 = sigmoidf_(g0[3]) * tanhf_(cc0);
        cc1 = fmaf(sigmoidf_(g1[2] + 1.0f), cc1, sigmoidf_(g1[0]) * tanhf_(g1[1]));
        const float h1 = sigmoidf_(g1[3]) * tanhf_(cc1);

        // ---- pack own h-chunk (A-frag order) and store ----
        const float h0n = __shfl_xor(h0, 1, 64);
        const float h1n = __shfl_xor(h1, 1, 64);
        if ((eu & 1) == 0) {
            const int bufw  = (t + 1) & 1;
            const int basew = ((bufw * NGRP + g) * NSLC + s) * 512 + er * 16;
            const uint32_t hi0 = bf16rne(h0),  hi0n = bf16rne(h0n);
            const uint32_t hi1 = bf16rne(h1),  hi1n = bf16rne(h1n);
            const uint32_t lo0  = bf16rne(h0  - bf16tof(hi0));
            const uint32_t lo0n = bf16rne(h0n - bf16tof(hi0n));
            const uint32_t lo1  = bf16rne(h1  - bf16tof(hi1));
            const uint32_t lo1n = bf16rne(h1n - bf16tof(hi1n));
            const int D0 = eu >> 1, D1 = 8 + (eu >> 1);
            __hip_atomic_store(&hx[basew + D0], hi0 | (hi0n << 16),
                               __ATOMIC_RELAXED, __HIP_MEMORY_SCOPE_AGENT);
            __hip_atomic_store(&hx[basew + D1], hi1 | (hi1n << 16),
                               __ATOMIC_RELAXED, __HIP_MEMORY_SCOPE_AGENT);
            __hip_atomic_store(&hx[basew + 256 + D0], lo0 | (lo0n << 16),
                               __ATOMIC_RELAXED, __HIP_MEMORY_SCOPE_AGENT);
            __hip_atomic_store(&hx[basew + 256 + D1], lo1 | (lo1n << 16),
                               __ATOMIC_RELAXED, __HIP_MEMORY_SCOPE_AGENT);
        }
        __syncthreads();   // drains vmcnt(0): chunk stores at coherent point
        if (tid == 0) {
            __hip_atomic_store(&tags[g * 8 + s], (uint32_t)(t + 1),
                               __ATOMIC_RELAXED, __HIP_MEMORY_SCOPE_AGENT);
        }
    }
}

// One block per batch row: dense = relu(h @ W_dense + b); logits = dense @ W_pred + b
__global__ __launch_bounds__(256, 1)
void head_kernel(const uint32_t* __restrict__ hx,
                 const float* __restrict__ W_dense,
                 const float* __restrict__ b_dense,
                 const float* __restrict__ W_pred,
                 const float* __restrict__ b_pred,
                 float* __restrict__ out) {
    __shared__ float hs[HID];
    __shared__ float ds[DNS];
    __shared__ float red[4];

    const int b = blockIdx.x;
    const int g = b >> 4, er = b & 15;
    const int tid = threadIdx.x;

    {   // reconstruct h = hi + lo from buf 0 chunk of (g, slice s)
        const int s  = tid >> 5;
        const int uu = tid & 31;
        const int base = (g * NSLC + s) * 512 + er * 16;
        const uint32_t dh = __hip_atomic_load(&hx[base + (uu >> 1)],
                                              __ATOMIC_RELAXED, __HIP_MEMORY_SCOPE_AGENT);
        const uint32_t dl = __hip_atomic_load(&hx[base + 256 + (uu >> 1)],
                                              __ATOMIC_RELAXED, __HIP_MEMORY_SCOPE_AGENT);
        const int sh = (uu & 1) * 16;
        hs[tid] = bf16tof((dh >> sh) & 0xFFFFu) + bf16tof((dl >> sh) & 0xFFFFu);
    }
    __syncthreads();

    for (int d = tid; d < DNS; d += 256) {
        float acc = b_dense[d];
        for (int k = 0; k < HID; k += 4) {
            float4 h4 = *reinterpret_cast<const float4*>(&hs[k]);
            acc = fmaf(h4.x, W_dense[(k + 0) * DNS + d], acc);
            acc = fmaf(h4.y, W_dense[(k + 1) * DNS + d], acc);
            acc = fmaf(h4.z, W_dense[(k + 2) * DNS + d], acc);
            acc = fmaf(h4.w, W_dense[(k + 3) * DNS + d], acc);
        }
        ds[d] = fmaxf(acc, 0.0f);
    }
    __syncthreads();

    const int wid = tid >> 6, lane = tid & 63;
    for (int c = 0; c < NCLS; ++c) {
        float p = 0.0f;
        for (int k = tid; k < DNS; k += 256) {
            p = fmaf(ds[k], W_pred[k * NCLS + c], p);
        }
        #pragma unroll
        for (int off = 32; off > 0; off >>= 1) {
            p += __shfl_down(p, off, 64);
        }
        if (lane == 0) red[wid] = p;
        __syncthreads();
        if (tid == 0) {
            out[b * NCLS + c] = red[0] + red[1] + red[2] + red[3] + b_pred[c];
        }
        __syncthreads();
    }
}

extern "C" void kernel_launch(void* const* d_in, const int* in_sizes, int n_in,
                              void* d_out, int out_size, void* d_ws, size_t ws_size,
                              hipStream_t stream) {
    const float* X       = (const float*)d_in[0];
    const float* W_lstm  = (const float*)d_in[1];
    const float* b_lstm  = (const float*)d_in[2];
    const float* W_dense = (const float*)d_in[3];
    const float* b_dense = (const float*)d_in[4];
    const float* W_pred  = (const float*)d_in[5];
    const float* b_pred  = (const float*)d_in[6];
    float* out = (float*)d_out;

    uint32_t* hx   = (uint32_t*)d_ws;                 // 131072 dwords = 512 KB
    uint32_t* tags = hx + 131072;                     // 128 dwords

    hipMemsetAsync(hx, 0, NGRP * NSLC * 512 * sizeof(uint32_t), stream);   // h_0 = 0 (buf 0)
    hipMemsetAsync(tags, 0, NGRP * NSLC * sizeof(uint32_t), stream);

    lstm_mfma<<<NGRP * NSLC, 256, 0, stream>>>(X, W_lstm, b_lstm, hx, tags);
    head_kernel<<<BATCH, 256, 0, stream>>>(hx, W_dense, b_dense, W_pred, b_pred, out);
}